// Round 2
// baseline (1190.238 us; speedup 1.0000x reference)
//
#include <hip/hip_runtime.h>
#include <cstddef>
#include <cmath>

#define TAU_INV 20.0f
#define NMAT 36
#define BATCH 512
#define MROWS 18432   // 512 * 36

// ---------------------------------------------------------------------------
// Generic tiled fp32 GEMM:  C = act(X @ W^T + bias)
//   X: M x K, row stride ldx
//   W: N x K, row-major (row stride K)   (torch-style Linear weight)
//   C: M x N, row stride ldc
// ACT: 0 = relu, 1 = tanh
// BlockDim must be 256; (BM/TM)*(BN/TN) == 256.
// ---------------------------------------------------------------------------
template<int BM, int BN, int TM, int TN, int ACT>
__global__ __launch_bounds__(256)
void gemm_nt(const float* __restrict__ X, int ldx,
             const float* __restrict__ W,
             const float* __restrict__ bias,
             float* __restrict__ C, int ldc,
             int M, int N, int K)
{
    constexpr int BK = 16;
    __shared__ float As[BK][BM + 4];
    __shared__ float Bs[BK][BN + 4];

    const int tid = threadIdx.x;
    const int bm = blockIdx.x * BM;
    const int bn = blockIdx.y * BN;
    constexpr int NTX = BN / TN;   // threads along n
    const int tx = tid % NTX;
    const int ty = tid / NTX;

    float acc[TM][TN];
#pragma unroll
    for (int i = 0; i < TM; ++i)
#pragma unroll
        for (int j = 0; j < TN; ++j) acc[i][j] = 0.f;

    for (int k0 = 0; k0 < K; k0 += BK) {
        __syncthreads();
        // ---- stage A tile: BM rows x 16 k  (BM*4 float4 loads) ----
        for (int l = tid; l < BM * 4; l += 256) {
            int r  = l >> 2;
            int kq = (l & 3) << 2;
            int grow = bm + r;          // M divisible by BM for our shapes
            int gk = k0 + kq;
            float4 v = make_float4(0.f, 0.f, 0.f, 0.f);
            if (gk + 3 < K) {
                v = *(const float4*)(X + (size_t)grow * ldx + gk);
            } else {
                float t0 = (gk + 0 < K) ? X[(size_t)grow * ldx + gk + 0] : 0.f;
                float t1 = (gk + 1 < K) ? X[(size_t)grow * ldx + gk + 1] : 0.f;
                float t2 = (gk + 2 < K) ? X[(size_t)grow * ldx + gk + 2] : 0.f;
                float t3 = (gk + 3 < K) ? X[(size_t)grow * ldx + gk + 3] : 0.f;
                v = make_float4(t0, t1, t2, t3);
            }
            As[kq + 0][r] = v.x; As[kq + 1][r] = v.y;
            As[kq + 2][r] = v.z; As[kq + 3][r] = v.w;
        }
        // ---- stage B tile: BN rows (n) x 16 k ----
        for (int l = tid; l < BN * 4; l += 256) {
            int r  = l >> 2;
            int kq = (l & 3) << 2;
            int gn = bn + r;
            int gk = k0 + kq;
            float4 v = make_float4(0.f, 0.f, 0.f, 0.f);
            if (gn < N) {
                if (gk + 3 < K) {
                    v = *(const float4*)(W + (size_t)gn * K + gk);
                } else {
                    float t0 = (gk + 0 < K) ? W[(size_t)gn * K + gk + 0] : 0.f;
                    float t1 = (gk + 1 < K) ? W[(size_t)gn * K + gk + 1] : 0.f;
                    float t2 = (gk + 2 < K) ? W[(size_t)gn * K + gk + 2] : 0.f;
                    float t3 = (gk + 3 < K) ? W[(size_t)gn * K + gk + 3] : 0.f;
                    v = make_float4(t0, t1, t2, t3);
                }
            }
            Bs[kq + 0][r] = v.x; Bs[kq + 1][r] = v.y;
            Bs[kq + 2][r] = v.z; Bs[kq + 3][r] = v.w;
        }
        __syncthreads();

#pragma unroll
        for (int kk = 0; kk < BK; ++kk) {
            float a[TM], b[TN];
#pragma unroll
            for (int i = 0; i < TM; i += 4)
                *(float4*)&a[i] = *(const float4*)&As[kk][ty * TM + i];
#pragma unroll
            for (int j = 0; j < TN; j += 4)
                *(float4*)&b[j] = *(const float4*)&Bs[kk][tx * TN + j];
#pragma unroll
            for (int i = 0; i < TM; ++i)
#pragma unroll
                for (int j = 0; j < TN; ++j)
                    acc[i][j] = fmaf(a[i], b[j], acc[i][j]);
        }
    }

    // ---- epilogue: bias + activation ----
#pragma unroll
    for (int i = 0; i < TM; ++i) {
        int m = bm + ty * TM + i;
#pragma unroll
        for (int j = 0; j < TN; ++j) {
            int n = bn + tx * TN + j;
            if (n < N) {
                float v = acc[i][j] + bias[n];
                if (ACT == 0) v = fmaxf(v, 0.f);
                else          v = tanhf(v);
                C[(size_t)m * ldc + n] = v;
            }
        }
    }
}

// ---------------------------------------------------------------------------
// x_pos branch: relu(seq[:, :, 2560:2564]) -> concat cols [256, 260)
// ---------------------------------------------------------------------------
__global__ void pos_relu(const float* __restrict__ seq, float* __restrict__ cat)
{
    int idx = blockIdx.x * blockDim.x + threadIdx.x;
    if (idx < MROWS * 4) {
        int row = idx >> 2;
        int c   = idx & 3;
        float v = seq[(size_t)row * 3076 + 2560 + c];
        cat[(size_t)row * 388 + 256 + c] = fmaxf(v, 0.f);
    }
}

// ---------------------------------------------------------------------------
// Sinkhorn: per batch element b, A = exp(z*20); 20x { A -= lse(rows);
// A -= lse(cols); }; out = exp(A).   One block (256 thr) per batch elem.
// Reductions: 4 lanes per row/col (36*4 = 144 <= 256 threads).
// ---------------------------------------------------------------------------
__global__ __launch_bounds__(256)
void sinkhorn_kernel(const float* __restrict__ Z, float* __restrict__ out)
{
    __shared__ float A[NMAT][NMAT + 1];
    __shared__ float lse[NMAT];
    const int b = blockIdx.x;
    const int tid = threadIdx.x;
    const float* zb = Z + (size_t)b * NMAT * NMAT;

    for (int idx = tid; idx < NMAT * NMAT; idx += 256) {
        float z = zb[idx];
        A[idx / NMAT][idx % NMAT] = expf(z * TAU_INV);
    }
    __syncthreads();

    for (int it = 0; it < 20; ++it) {
        // ---- row logsumexp (over columns j): 4 lanes per row ----
        if (tid < NMAT * 4) {
            int r = tid >> 2, g = tid & 3;
            float m = -3.402823466e38f;
            for (int j = g; j < NMAT; j += 4) m = fmaxf(m, A[r][j]);
            m = fmaxf(m, __shfl_xor(m, 2, 4));
            m = fmaxf(m, __shfl_xor(m, 1, 4));
            float s = 0.f;
            for (int j = g; j < NMAT; j += 4) s += expf(A[r][j] - m);
            s += __shfl_xor(s, 2, 4);
            s += __shfl_xor(s, 1, 4);
            if (g == 0) lse[r] = m + logf(s);
        }
        __syncthreads();
        for (int idx = tid; idx < NMAT * NMAT; idx += 256)
            A[idx / NMAT][idx % NMAT] -= lse[idx / NMAT];
        __syncthreads();

        // ---- col logsumexp (over rows i): 4 lanes per col ----
        if (tid < NMAT * 4) {
            int c = tid >> 2, g = tid & 3;
            float m = -3.402823466e38f;
            for (int i = g; i < NMAT; i += 4) m = fmaxf(m, A[i][c]);
            m = fmaxf(m, __shfl_xor(m, 2, 4));
            m = fmaxf(m, __shfl_xor(m, 1, 4));
            float s = 0.f;
            for (int i = g; i < NMAT; i += 4) s += expf(A[i][c] - m);
            s += __shfl_xor(s, 2, 4);
            s += __shfl_xor(s, 1, 4);
            if (g == 0) lse[c] = m + logf(s);
        }
        __syncthreads();
        for (int idx = tid; idx < NMAT * NMAT; idx += 256)
            A[idx / NMAT][idx % NMAT] -= lse[idx % NMAT];
        __syncthreads();
    }

    for (int idx = tid; idx < NMAT * NMAT; idx += 256)
        out[(size_t)b * NMAT * NMAT + idx] = expf(A[idx / NMAT][idx % NMAT]);
}

// ---------------------------------------------------------------------------
extern "C" void kernel_launch(void* const* d_in, const int* in_sizes, int n_in,
                              void* d_out, int out_size, void* d_ws, size_t ws_size,
                              hipStream_t stream)
{
    const float* seq = (const float*)d_in[0];
    const float* W1t = (const float*)d_in[1];
    const float* b1t = (const float*)d_in[2];
    const float* W1v = (const float*)d_in[3];
    const float* b1v = (const float*)d_in[4];
    const float* W2v = (const float*)d_in[5];
    const float* b2v = (const float*)d_in[6];
    const float* W1s = (const float*)d_in[7];
    const float* b1s = (const float*)d_in[8];
    const float* Wfp = (const float*)d_in[9];
    const float* bfp = (const float*)d_in[10];
    const float* Wfc = (const float*)d_in[11];
    const float* bfc = (const float*)d_in[12];

    float* ws = (float*)d_ws;
    // layout (floats):
    //   vis1   : [0, 9437184)              18432*512
    //   concat : [9437184, 16588800)       18432*388
    //   h256   : [0, 4718592)              (reuses vis1 after vis2 done)
    //   logits : [4718592, 5382144)        (within old vis1 region)
    float* vis1   = ws;
    float* cat    = ws + 9437184;
    float* h256   = ws;
    float* logits = ws + 4718592;

    const int M = MROWS;
    dim3 blk(256);

    // vis branch layer 1: (M,2048)->512, relu   [the big one: 38.7 GF]
    gemm_nt<128, 128, 8, 8, 0><<<dim3(M / 128, 4), blk, 0, stream>>>(
        seq + 512, 3076, W1v, b1v, vis1, 512, M, 512, 2048);
    // txt branch: (M,512)->128, relu -> concat cols [0,128)
    gemm_nt<64, 64, 4, 4, 0><<<dim3(M / 64, 2), blk, 0, stream>>>(
        seq, 3076, W1t, b1t, cat, 388, M, 128, 512);
    // sen branch: (M,512)->128, relu -> concat cols [260,388)
    gemm_nt<64, 64, 4, 4, 0><<<dim3(M / 64, 2), blk, 0, stream>>>(
        seq + 2564, 3076, W1s, b1s, cat + 260, 388, M, 128, 512);
    // pos branch -> concat cols [256,260)
    pos_relu<<<dim3((M * 4 + 255) / 256), blk, 0, stream>>>(seq, cat);
    // vis branch layer 2: (M,512)->128, relu -> concat cols [128,256)
    gemm_nt<64, 64, 4, 4, 0><<<dim3(M / 64, 2), blk, 0, stream>>>(
        vis1, 512, W2v, b2v, cat + 128, 388, M, 128, 512);
    // fc_pos: (M,388)->256, relu
    gemm_nt<64, 64, 4, 4, 0><<<dim3(M / 64, 4), blk, 0, stream>>>(
        cat, 388, Wfp, bfp, h256, 256, M, 256, 388);
    // fc: (M,256)->36, tanh
    gemm_nt<64, 64, 4, 4, 1><<<dim3(M / 64, 1), blk, 0, stream>>>(
        h256, 256, Wfc, bfc, logits, 36, M, 36, 256);
    // sinkhorn, one block per batch element
    sinkhorn_kernel<<<dim3(BATCH), blk, 0, stream>>>(logits, (float*)d_out);
}

// Round 4
// 760.346 us; speedup vs baseline: 1.5654x; 1.5654x over previous
//
#include <hip/hip_runtime.h>
#include <cstddef>
#include <cstdint>
#include <cmath>

#define TAU_INV 20.0f
#define NMAT 36
#define BATCH 512
#define MROWS 18432   // 512 * 36
#define MHALF 9216

typedef unsigned short us16;
typedef __attribute__((ext_vector_type(8))) short s16x8;   // 8 bf16 = 4 VGPRs
typedef __attribute__((ext_vector_type(4))) float f32x4;

// ---------------- bf16 helpers (RNE) ----------------
__device__ inline us16 f2bf(float x) {
    uint32_t u = __float_as_uint(x);
    u += 0x7fff + ((u >> 16) & 1);
    return (us16)(u >> 16);
}
__device__ inline float bf2f(us16 h) {
    return __uint_as_float(((uint32_t)h) << 16);
}
// 3-way split: x ~= h + m + l, residual <= 2^-27 |x|
__device__ inline void split3(float v, us16& h, us16& m, us16& l) {
    h = f2bf(v);
    float r1 = v - bf2f(h);
    m = f2bf(r1);
    l = f2bf(r1 - bf2f(m));
}

// ---------------- async global->LDS 16B DMA ----------------
__device__ inline void dma16(const void* g, void* l) {
    __builtin_amdgcn_global_load_lds(
        (const __attribute__((address_space(1))) void*)g,
        (__attribute__((address_space(3))) void*)l, 16, 0, 0);
}

__device__ inline f32x4 mfma16(s16x8 a, s16x8 b, f32x4 c) {
    return __builtin_amdgcn_mfma_f32_16x16x32_bf16(a, b, c, 0, 0, 0);
}

// ---------------------------------------------------------------------------
// 3-way-split bf16 MFMA GEMM:  C = act(X @ W^T + bias)  (fp32-equivalent)
//   X: fp32 [M][ldx] (split on the fly during staging)
//   W: pre-split padded bf16 planes Bh/Bm/Bl, [N][K] row-major, K mult of 32
// OUT: 0 = relu (all cols valid), 1 = tanh with col < nreal store guard
// 256 threads = 4 waves, 2x2 wave grid; wave tile (BM/2)x(BN/2).
// ---------------------------------------------------------------------------
template<int BM, int BN, int OUT>
__global__ __launch_bounds__(256)
void gemm_split(const float* __restrict__ X, int ldx,
                const us16* __restrict__ Bh, const us16* __restrict__ Bm,
                const us16* __restrict__ Bl,
                const float* __restrict__ bias,
                float* __restrict__ C, int ldc, int nreal, int K)
{
    constexpr int MT  = BM / 32;      // 16-row m-tiles per wave
    constexpr int NT  = BN / 32;      // 16-col n-tiles per wave
    constexpr int NF4 = BM / 32;      // float4 A-loads per thread per k-tile
    constexpr int LB  = BN / 64;      // B DMA chunks per wave per plane

    alignas(16) __shared__ us16 lds[(BM + BN) * 96];
    us16* AsH = lds;
    us16* AsM = lds + BM * 32;
    us16* AsL = lds + BM * 64;
    us16* BsH = lds + BM * 96;
    us16* BsM = lds + BM * 96 + BN * 32;
    us16* BsL = lds + BM * 96 + BN * 64;

    const int tid  = threadIdx.x;
    const int lane = tid & 63;
    const int wid  = tid >> 6;
    const int bm   = blockIdx.x * BM;
    const int bn   = blockIdx.y * BN;
    const int lm   = lane & 15;       // fragment row/col within 16
    const int kb   = lane >> 4;       // k-quad 0..3
    const int wm   = (wid >> 1) * (BM / 2);
    const int wn   = (wid & 1) * (BN / 2);

    // A staging map: thread covers rows arow + i*32, cols acol..acol+3
    const int arow = tid >> 3;        // 0..31
    const int acol = (tid & 7) * 4;   // 0,4,..,28

    f32x4 acc[MT][NT];
#pragma unroll
    for (int i = 0; i < MT; ++i)
#pragma unroll
        for (int j = 0; j < NT; ++j) acc[i][j] = (f32x4){0.f, 0.f, 0.f, 0.f};

    float4 pref[NF4];
#pragma unroll
    for (int i = 0; i < NF4; ++i)
        pref[i] = *(const float4*)(X + (size_t)(bm + i * 32 + arow) * ldx + acol);

    for (int k0 = 0; k0 < K; k0 += 32) {
        __syncthreads();   // previous compute done; LDS reusable
        // ---- split prefetched A into hi/mid/lo LDS planes ----
#pragma unroll
        for (int i = 0; i < NF4; ++i) {
            const int r = i * 32 + arow;
            float vs[4] = {pref[i].x, pref[i].y, pref[i].z, pref[i].w};
            us16 h[4], m[4], l[4];
#pragma unroll
            for (int j = 0; j < 4; ++j) split3(vs[j], h[j], m[j], l[j]);
            *(ushort4*)&AsH[r * 32 + acol] = make_ushort4(h[0], h[1], h[2], h[3]);
            *(ushort4*)&AsM[r * 32 + acol] = make_ushort4(m[0], m[1], m[2], m[3]);
            *(ushort4*)&AsL[r * 32 + acol] = make_ushort4(l[0], l[1], l[2], l[3]);
        }
        // ---- async DMA B tile (3 planes) ----
#pragma unroll
        for (int q = 0; q < LB; ++q) {
            const int rb = wid * (LB * 16) + q * 16;          // wave-uniform
            const int gr = bn + rb + (lane >> 2);
            const int gc = k0 + (lane & 3) * 8;
            dma16(Bh + (size_t)gr * K + gc, &BsH[rb * 32]);
            dma16(Bm + (size_t)gr * K + gc, &BsM[rb * 32]);
            dma16(Bl + (size_t)gr * K + gc, &BsL[rb * 32]);
        }
        // ---- prefetch A for next k-tile ----
        if (k0 + 32 < K) {
#pragma unroll
            for (int i = 0; i < NF4; ++i)
                pref[i] = *(const float4*)(X + (size_t)(bm + i * 32 + arow) * ldx
                                           + (k0 + 32) + acol);
        }
        __syncthreads();   // staging visible (compiler drains vmcnt+lgkm)

        // ---- MFMA phase: 6 product tiers (hh, hm, mh, hl, mm, lh) ----
        s16x8 ah[MT], am[MT], al[MT];
#pragma unroll
        for (int mt = 0; mt < MT; ++mt) {
            const int off = (wm + mt * 16 + lm) * 32 + kb * 8;
            ah[mt] = *(const s16x8*)&AsH[off];
            am[mt] = *(const s16x8*)&AsM[off];
            al[mt] = *(const s16x8*)&AsL[off];
        }
#pragma unroll
        for (int nt = 0; nt < NT; ++nt) {
            const int off = (wn + nt * 16 + lm) * 32 + kb * 8;
            s16x8 bh = *(const s16x8*)&BsH[off];
            s16x8 bm = *(const s16x8*)&BsM[off];
            s16x8 bl = *(const s16x8*)&BsL[off];
#pragma unroll
            for (int mt = 0; mt < MT; ++mt) {
                acc[mt][nt] = mfma16(ah[mt], bh, acc[mt][nt]);
                acc[mt][nt] = mfma16(ah[mt], bm, acc[mt][nt]);
                acc[mt][nt] = mfma16(am[mt], bh, acc[mt][nt]);
                acc[mt][nt] = mfma16(ah[mt], bl, acc[mt][nt]);
                acc[mt][nt] = mfma16(am[mt], bm, acc[mt][nt]);
                acc[mt][nt] = mfma16(al[mt], bh, acc[mt][nt]);
            }
        }
    }

    // ---- epilogue: bias + activation (C/D map: col=lane&15, row=quad*4+r) ----
    float bv[NT];
#pragma unroll
    for (int nt = 0; nt < NT; ++nt) {
        const int col = bn + wn + nt * 16 + lm;
        bv[nt] = (col < nreal) ? bias[col] : 0.f;
    }
#pragma unroll
    for (int nt = 0; nt < NT; ++nt) {
        const int col = bn + wn + nt * 16 + lm;
#pragma unroll
        for (int mt = 0; mt < MT; ++mt) {
#pragma unroll
            for (int r = 0; r < 4; ++r) {
                const int row = bm + wm + mt * 16 + kb * 4 + r;
                float v = acc[mt][nt][r] + bv[nt];
                if (OUT == 0) {
                    C[(size_t)row * ldc + col] = fmaxf(v, 0.f);
                } else {
                    if (col < nreal)
                        C[(size_t)row * ldc + col] = tanhf(v);
                }
            }
        }
    }
}

// ---------------------------------------------------------------------------
// Weight pre-split into padded bf16 hi/mid/lo planes.
// Plane layout (ushort offsets): w1v [512x2048] @0, w1t @1048576, w1s @1114112,
// w2v @1179648, wfp [256x416 pad] @1245184, wfc [64x256 pad] @1351680; tot 1368064
// ---------------------------------------------------------------------------
#define WOFF_W1T 1048576
#define WOFF_W1S 1114112
#define WOFF_W2V 1179648
#define WOFF_WFP 1245184
#define WOFF_WFC 1351680
#define WTOT     1368064

__global__ void split_weights(const float* __restrict__ w1v, const float* __restrict__ w1t,
                              const float* __restrict__ w1s, const float* __restrict__ w2v,
                              const float* __restrict__ wfp, const float* __restrict__ wfc,
                              us16* __restrict__ hi, us16* __restrict__ mi,
                              us16* __restrict__ lo)
{
    int idx = blockIdx.x * 256 + threadIdx.x;
    if (idx >= WTOT) return;
    const float* src; int N, K, Kp; int local;
    if (idx < WOFF_W1T)      { src = w1v; N = 512; K = 2048; Kp = 2048; local = idx; }
    else if (idx < WOFF_W1S) { src = w1t; N = 128; K = 512;  Kp = 512;  local = idx - WOFF_W1T; }
    else if (idx < WOFF_W2V) { src = w1s; N = 128; K = 512;  Kp = 512;  local = idx - WOFF_W1S; }
    else if (idx < WOFF_WFP) { src = w2v; N = 128; K = 512;  Kp = 512;  local = idx - WOFF_W2V; }
    else if (idx < WOFF_WFC) { src = wfp; N = 256; K = 388;  Kp = 416;  local = idx - WOFF_WFP; }
    else                     { src = wfc; N = 36;  K = 256;  Kp = 256;  local = idx - WOFF_WFC; }
    int n = local / Kp, k = local % Kp;
    float v = (n < N && k < K) ? src[(size_t)n * K + k] : 0.f;
    us16 h, m, l;
    split3(v, h, m, l);
    hi[idx] = h; mi[idx] = m; lo[idx] = l;
}

// ---------------------------------------------------------------------------
// pos branch + cat K-padding: cat cols [256,260) = relu(pos), [388,416) = 0
// ---------------------------------------------------------------------------
__global__ void pos_pad(const float* __restrict__ seq, float* __restrict__ cat)
{
    int idx = blockIdx.x * 256 + threadIdx.x;
    if (idx >= MROWS * 32) return;
    int row = idx >> 5, j = idx & 31;
    if (j < 4) {
        float v = seq[(size_t)row * 3076 + 2560 + j];
        cat[(size_t)row * 416 + 256 + j] = fmaxf(v, 0.f);
    } else {
        cat[(size_t)row * 416 + 388 + (j - 4)] = 0.f;
    }
}

// ---------------------------------------------------------------------------
// Sinkhorn (verified in R2)
// ---------------------------------------------------------------------------
__global__ __launch_bounds__(256)
void sinkhorn_kernel(const float* __restrict__ Z, float* __restrict__ out)
{
    __shared__ float A[NMAT][NMAT + 1];
    __shared__ float lse[NMAT];
    const int b = blockIdx.x;
    const int tid = threadIdx.x;
    const float* zb = Z + (size_t)b * NMAT * NMAT;

    for (int idx = tid; idx < NMAT * NMAT; idx += 256)
        A[idx / NMAT][idx % NMAT] = expf(zb[idx] * TAU_INV);
    __syncthreads();

    for (int it = 0; it < 20; ++it) {
        if (tid < NMAT * 4) {
            int r = tid >> 2, g = tid & 3;
            float m = -3.402823466e38f;
            for (int j = g; j < NMAT; j += 4) m = fmaxf(m, A[r][j]);
            m = fmaxf(m, __shfl_xor(m, 2, 4));
            m = fmaxf(m, __shfl_xor(m, 1, 4));
            float s = 0.f;
            for (int j = g; j < NMAT; j += 4) s += expf(A[r][j] - m);
            s += __shfl_xor(s, 2, 4);
            s += __shfl_xor(s, 1, 4);
            if (g == 0) lse[r] = m + logf(s);
        }
        __syncthreads();
        for (int idx = tid; idx < NMAT * NMAT; idx += 256)
            A[idx / NMAT][idx % NMAT] -= lse[idx / NMAT];
        __syncthreads();

        if (tid < NMAT * 4) {
            int c = tid >> 2, g = tid & 3;
            float m = -3.402823466e38f;
            for (int i = g; i < NMAT; i += 4) m = fmaxf(m, A[i][c]);
            m = fmaxf(m, __shfl_xor(m, 2, 4));
            m = fmaxf(m, __shfl_xor(m, 1, 4));
            float s = 0.f;
            for (int i = g; i < NMAT; i += 4) s += expf(A[i][c] - m);
            s += __shfl_xor(s, 2, 4);
            s += __shfl_xor(s, 1, 4);
            if (g == 0) lse[c] = m + logf(s);
        }
        __syncthreads();
        for (int idx = tid; idx < NMAT * NMAT; idx += 256)
            A[idx / NMAT][idx % NMAT] -= lse[idx % NMAT];
        __syncthreads();
    }

    for (int idx = tid; idx < NMAT * NMAT; idx += 256)
        out[(size_t)b * NMAT * NMAT + idx] = expf(A[idx / NMAT][idx % NMAT]);
}

// ---------------------------------------------------------------------------
extern "C" void kernel_launch(void* const* d_in, const int* in_sizes, int n_in,
                              void* d_out, int out_size, void* d_ws, size_t ws_size,
                              hipStream_t stream)
{
    const float* seq = (const float*)d_in[0];
    const float* W1t = (const float*)d_in[1];
    const float* b1t = (const float*)d_in[2];
    const float* W1v = (const float*)d_in[3];
    const float* b1v = (const float*)d_in[4];
    const float* W2v = (const float*)d_in[5];
    const float* b2v = (const float*)d_in[6];
    const float* W1s = (const float*)d_in[7];
    const float* b1s = (const float*)d_in[8];
    const float* Wfp = (const float*)d_in[9];
    const float* bfp = (const float*)d_in[10];
    const float* Wfc = (const float*)d_in[11];
    const float* bfc = (const float*)d_in[12];

    float* wsF = (float*)d_ws;
    // ws layout (float offsets):
    //   [0, 4718592)        : vis1half (9216x512); later h256 (18432x256)
    //   [4718592, 12386304) : cat (18432x416); later logits (18432x36)
    //   [12386304, +2052096): weight planes hi/mid/lo (3 x WTOT ushorts)
    //   total 57.8 MB (R2 used 66.4 MB successfully)
    float* vis1buf = wsF;
    float* h256    = wsF;
    float* cat     = wsF + 4718592;
    float* logits  = wsF + 4718592;   // overlays cat (dead when fc runs)
    us16*  Whi     = (us16*)(wsF + 12386304);
    us16*  Wmi     = Whi + WTOT;
    us16*  Wlo     = Wmi + WTOT;

    dim3 blk(256);

    // 1. pre-split weights into padded bf16 planes
    split_weights<<<dim3((WTOT + 255) / 256), blk, 0, stream>>>(
        W1v, W1t, W1s, W2v, Wfp, Wfc, Whi, Wmi, Wlo);
    // 2. pos branch + cat pad cols
    pos_pad<<<dim3((MROWS * 32 + 255) / 256), blk, 0, stream>>>(seq, cat);
    // 3. txt: (M,512)->128 relu -> cat[:,0:128)
    gemm_split<64, 128, 0><<<dim3(MROWS / 64, 1), blk, 0, stream>>>(
        seq, 3076, Whi + WOFF_W1T, Wmi + WOFF_W1T, Wlo + WOFF_W1T, b1t,
        cat, 416, 128, 512);
    // 4. sen: (M,512)->128 relu -> cat[:,260:388)
    gemm_split<64, 128, 0><<<dim3(MROWS / 64, 1), blk, 0, stream>>>(
        seq + 2564, 3076, Whi + WOFF_W1S, Wmi + WOFF_W1S, Wlo + WOFF_W1S, b1s,
        cat + 260, 416, 128, 512);
    // 5-8. vis branch in two M-halves (ws capacity)
    for (int h = 0; h < 2; ++h) {
        const float* xh = seq + 512 + (size_t)h * MHALF * 3076;
        float* ch = cat + 128 + (size_t)h * MHALF * 416;
        gemm_split<64, 128, 0><<<dim3(MHALF / 64, 4), blk, 0, stream>>>(
            xh, 3076, Whi, Wmi, Wlo, b1v, vis1buf, 512, 512, 2048);
        gemm_split<64, 128, 0><<<dim3(MHALF / 64, 1), blk, 0, stream>>>(
            vis1buf, 512, Whi + WOFF_W2V, Wmi + WOFF_W2V, Wlo + WOFF_W2V, b2v,
            ch, 416, 128, 512);
    }
    // 9. fc_pos: (M,416)->256 relu -> h256 (overlays vis1buf, now dead)
    gemm_split<64, 128, 0><<<dim3(MROWS / 64, 2), blk, 0, stream>>>(
        cat, 416, Whi + WOFF_WFP, Wmi + WOFF_WFP, Wlo + WOFF_WFP, bfp,
        h256, 256, 256, 416);
    // 10. fc: (M,256)->36 tanh -> logits (overlays cat, now dead)
    gemm_split<64, 64, 1><<<dim3(MROWS / 64, 1), blk, 0, stream>>>(
        h256, 256, Whi + WOFF_WFC, Wmi + WOFF_WFC, Wlo + WOFF_WFC, bfc,
        logits, 36, 36, 256);
    // 11. sinkhorn
    sinkhorn_kernel<<<dim3(BATCH), blk, 0, stream>>>(logits, (float*)d_out);
}